// Round 12
// baseline (446.227 us; speedup 1.0000x reference)
//
#include <hip/hip_runtime.h>
#include <hip/hip_bf16.h>

#define N_NODES 50000
#define E_EDGES 800000
#define NCLS 10
#define SCAN_BLOCKS 196   // 196*256 = 50176 >= N_NODES
#define GAT_BLOCKS 2048   // x4 waves = 8192 persistent waves = 32/CU

typedef short bfrag __attribute__((ext_vector_type(8)));   // 8 bf16 in 4 VGPRs
typedef float f32x4 __attribute__((ext_vector_type(4)));

__device__ __forceinline__ int rfl(int v) { return __builtin_amdgcn_readfirstlane(v); }

// ---------- bf16 split helpers ----------
__device__ __forceinline__ unsigned short bf16rne(float x) {
    unsigned u = __float_as_uint(x);
    unsigned r = u + 0x7FFFu + ((u >> 16) & 1u);
    return (unsigned short)(r >> 16);
}

// ---------- DPP wave-64 sum reductions ----------
template <int CTRL, int RM>
__device__ __forceinline__ float dppadd(float x) {
    int s = __builtin_amdgcn_update_dpp(0, __float_as_int(x), CTRL, RM, 0xf, true);
    return x + __int_as_float(s);
}
__device__ __forceinline__ float rl63(float x) {
    return __int_as_float(__builtin_amdgcn_readlane(__float_as_int(x), 63));
}
__device__ __forceinline__ float rl31(float x) {
    return __int_as_float(__builtin_amdgcn_readlane(__float_as_int(x), 31));
}
// full 64-lane reduce (total in lane 63): 6 stages
__device__ __forceinline__ void dred1(float& x0) {
    x0 = dppadd<0x111, 0xf>(x0);
    x0 = dppadd<0x112, 0xf>(x0);
    x0 = dppadd<0x114, 0xf>(x0);
    x0 = dppadd<0x118, 0xf>(x0);
    x0 = dppadd<0x142, 0xa>(x0);
    x0 = dppadd<0x143, 0xc>(x0);
}
__device__ __forceinline__ void dred4(float& x0, float& x1, float& x2, float& x3) {
    x0 = dppadd<0x111, 0xf>(x0); x1 = dppadd<0x111, 0xf>(x1);
    x2 = dppadd<0x111, 0xf>(x2); x3 = dppadd<0x111, 0xf>(x3);
    x0 = dppadd<0x112, 0xf>(x0); x1 = dppadd<0x112, 0xf>(x1);
    x2 = dppadd<0x112, 0xf>(x2); x3 = dppadd<0x112, 0xf>(x3);
    x0 = dppadd<0x114, 0xf>(x0); x1 = dppadd<0x114, 0xf>(x1);
    x2 = dppadd<0x114, 0xf>(x2); x3 = dppadd<0x114, 0xf>(x3);
    x0 = dppadd<0x118, 0xf>(x0); x1 = dppadd<0x118, 0xf>(x1);
    x2 = dppadd<0x118, 0xf>(x2); x3 = dppadd<0x118, 0xf>(x3);
    x0 = dppadd<0x142, 0xa>(x0); x1 = dppadd<0x142, 0xa>(x1);
    x2 = dppadd<0x142, 0xa>(x2); x3 = dppadd<0x142, 0xa>(x3);
    x0 = dppadd<0x143, 0xc>(x0); x1 = dppadd<0x143, 0xc>(x1);
    x2 = dppadd<0x143, 0xc>(x2); x3 = dppadd<0x143, 0xc>(x3);
}
// half-wave reduce, 5 stages: lane31 = sum(lanes 0-31), lane63 = sum(lanes 32-63)
__device__ __forceinline__ void dredH(float& x) {
    x = dppadd<0x111, 0xf>(x);
    x = dppadd<0x112, 0xf>(x);
    x = dppadd<0x114, 0xf>(x);
    x = dppadd<0x118, 0xf>(x);
    x = dppadd<0x142, 0xa>(x);
}
__device__ __forceinline__ void dredH4(float& x, float& y, float& z, float& w) {
    x = dppadd<0x111, 0xf>(x); y = dppadd<0x111, 0xf>(y);
    z = dppadd<0x111, 0xf>(z); w = dppadd<0x111, 0xf>(w);
    x = dppadd<0x112, 0xf>(x); y = dppadd<0x112, 0xf>(y);
    z = dppadd<0x112, 0xf>(z); w = dppadd<0x112, 0xf>(w);
    x = dppadd<0x114, 0xf>(x); y = dppadd<0x114, 0xf>(y);
    z = dppadd<0x114, 0xf>(z); w = dppadd<0x114, 0xf>(w);
    x = dppadd<0x118, 0xf>(x); y = dppadd<0x118, 0xf>(y);
    z = dppadd<0x118, 0xf>(z); w = dppadd<0x118, 0xf>(w);
    x = dppadd<0x142, 0xa>(x); y = dppadd<0x142, 0xa>(y);
    z = dppadd<0x142, 0xa>(z); w = dppadd<0x142, 0xa>(w);
}
__device__ __forceinline__ float lrelu(float u) { return u > 0.f ? u : 0.2f * u; }
// packed edge score partial: sum over 2 packed comps of lrelu(v+xr)*a
__device__ __forceinline__ float escore(float2 v, float2 xr2, float2 av) {
    float ux = v.x + xr2.x, uy = v.y + xr2.y;
    ux = fmaxf(ux, 0.2f * ux);
    uy = fmaxf(uy, 0.2f * uy);
    return ux * av.x + uy * av.y;
}

// ---------- CSR build ----------
__global__ void k_count(const int* __restrict__ dst, int* __restrict__ deg) {
    int i = blockIdx.x * blockDim.x + threadIdx.x;
    if (i < E_EDGES) {
        unsigned d = (unsigned)dst[i];
        if (d < N_NODES) atomicAdd(&deg[d], 1);
    }
}

// hierarchical exclusive scan, 3 passes, all parallel
__global__ void k_scanA(const int* __restrict__ deg, int* __restrict__ incl,
                        int* __restrict__ bsum) {
    __shared__ int s[256];
    int i = blockIdx.x * 256 + threadIdx.x;
    int v = (i < N_NODES) ? deg[i] : 0;
    s[threadIdx.x] = v;
    __syncthreads();
    for (int off = 1; off < 256; off <<= 1) {
        int t = (threadIdx.x >= off) ? s[threadIdx.x - off] : 0;
        __syncthreads();
        s[threadIdx.x] += t;
        __syncthreads();
    }
    if (i < N_NODES) incl[i] = s[threadIdx.x];
    if (threadIdx.x == 255) bsum[blockIdx.x] = s[255];
}

__global__ void k_scanB(int* __restrict__ bsum) {
    __shared__ int s[256];
    int t = threadIdx.x;
    s[t] = (t < SCAN_BLOCKS) ? bsum[t] : 0;
    __syncthreads();
    for (int off = 1; off < 256; off <<= 1) {
        int v = (t >= off) ? s[t - off] : 0;
        __syncthreads();
        s[t] += v;
        __syncthreads();
    }
    if (t < SCAN_BLOCKS) bsum[t] = s[t];  // inclusive block sums
}

__global__ void k_scanC(int* __restrict__ degcur, const int* __restrict__ incl,
                        const int* __restrict__ bsum, int* __restrict__ rowptr) {
    int i = blockIdx.x * 256 + threadIdx.x;
    if (i >= N_NODES) return;
    int base = (blockIdx.x == 0) ? 0 : bsum[blockIdx.x - 1];
    int d = degcur[i];
    int excl = base + incl[i] - d;
    rowptr[i] = excl;
    degcur[i] = excl;  // cursor init
    if (i == N_NODES - 1) rowptr[N_NODES] = base + incl[i];
}

__global__ void k_scatter(const int* __restrict__ src, const int* __restrict__ dst,
                          int* __restrict__ cursor, int* __restrict__ csr_src) {
    int i = blockIdx.x * blockDim.x + threadIdx.x;
    if (i < E_EDGES) {
        unsigned d = (unsigned)dst[i];
        if (d < N_NODES) {
            int p = atomicAdd(&cursor[d], 1);
            unsigned s = (unsigned)src[i];
            csr_src[p] = (s < N_NODES) ? (int)s : 0;
        }
    }
}

// ---------- split fp32 weight -> hi/lo bf16 ----------
__global__ void k_splitW(const float* __restrict__ W, int n,
                         short* __restrict__ hi, short* __restrict__ lo) {
    int i = blockIdx.x * 256 + threadIdx.x;
    if (i < n) {
        float x = W[i];
        unsigned short h = bf16rne(x);
        float hf = __uint_as_float((unsigned)h << 16);
        unsigned short l = bf16rne(x - hf);
        hi[i] = (short)h;
        lo[i] = (short)l;
    }
}

// ---------- MFMA GEMM, single side (split-bf16 fp32 emulation) ----------
template <int NOUT>
__global__ __launch_bounds__(256) void k_mgemmS(const float* __restrict__ X,
                                                const short* __restrict__ whi,
                                                const short* __restrict__ wlo,
                                                const float* __restrict__ b,
                                                float* __restrict__ Y, int nrows) {
    const int NCT = 4;
    int tid = threadIdx.x;
    int wv = tid >> 6, lane = tid & 63;
    int m = lane & 15, g = lane >> 4;
    int colbase = blockIdx.y * 64;
    int row = blockIdx.x * 64 + wv * 16 + m;
    int rowc = min(row, nrows - 1);

    bfrag ahi[4], alo[4];
    const float* xp = X + (size_t)rowc * 128 + g * 8;
#pragma unroll
    for (int kb = 0; kb < 4; ++kb) {
        float4 u0 = *(const float4*)(xp + kb * 32);
        float4 u1 = *(const float4*)(xp + kb * 32 + 4);
        float xs[8] = {u0.x, u0.y, u0.z, u0.w, u1.x, u1.y, u1.z, u1.w};
#pragma unroll
        for (int j = 0; j < 8; ++j) {
            unsigned short h = bf16rne(xs[j]);
            float hf = __uint_as_float((unsigned)h << 16);
            unsigned short l = bf16rne(xs[j] - hf);
            ahi[kb][j] = (short)h;
            alo[kb][j] = (short)l;
        }
    }

    f32x4 acc[NCT];
#pragma unroll
    for (int ct = 0; ct < NCT; ++ct) acc[ct] = (f32x4){0.f, 0.f, 0.f, 0.f};

#pragma unroll
    for (int kb = 0; kb < 4; ++kb) {
#pragma unroll
        for (int ct = 0; ct < NCT; ++ct) {
            size_t wo = (size_t)(colbase + ct * 16 + m) * 128 + kb * 32 + g * 8;
            bfrag bh = *(const bfrag*)(whi + wo);
            bfrag bl_ = *(const bfrag*)(wlo + wo);
            acc[ct] = __builtin_amdgcn_mfma_f32_16x16x32_bf16(ahi[kb], bh, acc[ct], 0, 0, 0);
            acc[ct] = __builtin_amdgcn_mfma_f32_16x16x32_bf16(alo[kb], bh, acc[ct], 0, 0, 0);
            acc[ct] = __builtin_amdgcn_mfma_f32_16x16x32_bf16(ahi[kb], bl_, acc[ct], 0, 0, 0);
        }
    }

    int orow0 = blockIdx.x * 64 + wv * 16 + g * 4;
#pragma unroll
    for (int ct = 0; ct < NCT; ++ct) {
        int col = colbase + ct * 16 + m;
        float bv = b[col];
#pragma unroll
        for (int i = 0; i < 4; ++i) {
            int orow = orow0 + i;
            if (orow < nrows) Y[(size_t)orow * NOUT + col] = acc[ct][i] + bv;
        }
    }
}

// ---------- GATv2 layer 1: H=2, C=64, concat -> out[N][128], fused bias+ELU ----------
// float2-packed halves + persistent grid-stride waves + 4-edge batching.
__global__ __launch_bounds__(256) void k_gat1(const float* __restrict__ xl,
                                              const float* __restrict__ xr,
                                              const int* __restrict__ rowptr,
                                              const int* __restrict__ csr,
                                              const float* __restrict__ att,
                                              const float* __restrict__ bias,
                                              float* __restrict__ out) {
    int lane = threadIdx.x & 63;
    bool lo = lane < 32;
    int waveId = blockIdx.x * 4 + (threadIdx.x >> 6);
    const int NW = GAT_BLOCKS * 4;
    const float2* xl2 = (const float2*)xl;
    float2 av = ((const float2*)att)[lane];
    float2 b2 = ((const float2*)bias)[lane];

    for (int node = waveId; node < N_NODES; node += NW) {
        size_t nb = (size_t)node * 64;   // row offset in float2 units (128 floats)
        float2 xr2 = ((const float2*)xr)[nb + lane];
        float2 sl2 = xl2[nb + lane];

        // self loop
        float p = escore(sl2, xr2, av);
        dredH(p);
        float sv = lo ? rl31(p) : rl63(p);
        float ev = __expf(sv);
        float den = ev;
        float2 acc;
        acc.x = ev * sl2.x;
        acc.y = ev * sl2.y;

        int beg = rfl(rowptr[node]), end = rfl(rowptr[node + 1]);
        int cnt = end - beg;
        const int* cp = csr + beg;
        int nq = cnt >> 2;
        if (nq > 0) {
            int i0 = rfl(cp[0]), i1 = rfl(cp[1]), i2 = rfl(cp[2]), i3 = rfl(cp[3]);
            float2 A = xl2[(size_t)(unsigned)i0 * 64 + lane];
            float2 B = xl2[(size_t)(unsigned)i1 * 64 + lane];
            float2 C = xl2[(size_t)(unsigned)i2 * 64 + lane];
            float2 D = xl2[(size_t)(unsigned)i3 * 64 + lane];
            for (int q = 1; q <= nq; ++q) {
                float2 nA = {0.f, 0.f}, nB = {0.f, 0.f}, nC = {0.f, 0.f}, nD = {0.f, 0.f};
                if (q < nq) {
                    int j0 = rfl(cp[4 * q]), j1 = rfl(cp[4 * q + 1]);
                    int j2 = rfl(cp[4 * q + 2]), j3 = rfl(cp[4 * q + 3]);
                    nA = xl2[(size_t)(unsigned)j0 * 64 + lane];
                    nB = xl2[(size_t)(unsigned)j1 * 64 + lane];
                    nC = xl2[(size_t)(unsigned)j2 * 64 + lane];
                    nD = xl2[(size_t)(unsigned)j3 * 64 + lane];
                }
                float pa = escore(A, xr2, av);
                float pb = escore(B, xr2, av);
                float pc = escore(C, xr2, av);
                float pd = escore(D, xr2, av);
                dredH4(pa, pb, pc, pd);
                float sa = lo ? rl31(pa) : rl63(pa);
                float sb = lo ? rl31(pb) : rl63(pb);
                float sc = lo ? rl31(pc) : rl63(pc);
                float sd = lo ? rl31(pd) : rl63(pd);
                float ea = __expf(sa), eb = __expf(sb);
                float ec = __expf(sc), ed = __expf(sd);
                den += (ea + eb) + (ec + ed);
                acc.x = fmaf(ea, A.x, fmaf(eb, B.x, fmaf(ec, C.x, fmaf(ed, D.x, acc.x))));
                acc.y = fmaf(ea, A.y, fmaf(eb, B.y, fmaf(ec, C.y, fmaf(ed, D.y, acc.y))));
                A = nA; B = nB; C = nC; D = nD;
            }
        }
        for (int r = cnt & ~3; r < cnt; ++r) {
            int j = rfl(cp[r]);
            float2 Cv = xl2[(size_t)(unsigned)j * 64 + lane];
            float pc = escore(Cv, xr2, av);
            dredH(pc);
            float sc = lo ? rl31(pc) : rl63(pc);
            float ec = __expf(sc);
            den += ec;
            acc.x = fmaf(ec, Cv.x, acc.x);
            acc.y = fmaf(ec, Cv.y, acc.y);
        }
        float ox = acc.x / den + b2.x;
        float oy = acc.y / den + b2.y;
        ox = ox > 0.f ? ox : expm1f(ox);
        oy = oy > 0.f ? oy : expm1f(oy);
        float2 o2 = {ox, oy};
        ((float2*)out)[nb + lane] = o2;
    }
}

// ---------- GATv2 layer 2: H=1, C=64 -> out[N][64], fused bias+ELU ----------
__global__ __launch_bounds__(256) void k_gat2(const float* __restrict__ xl,
                                              const float* __restrict__ xr,
                                              const int* __restrict__ rowptr,
                                              const int* __restrict__ csr,
                                              const float* __restrict__ att,
                                              const float* __restrict__ bias,
                                              float* __restrict__ out) {
    int lane = threadIdx.x & 63;
    int waveId = blockIdx.x * 4 + (threadIdx.x >> 6);
    const int NW = GAT_BLOCKS * 4;
    float a = att[lane];
    float bv = bias[lane];

    for (int node = waveId; node < N_NODES; node += NW) {
        size_t nb = (size_t)node << 6;
        float xrv = xr[nb + lane];
        float slv = xl[nb + lane];
        float p = lrelu(slv + xrv) * a;
        dred1(p);
        float w = __expf(rl63(p));
        float den = w;
        float acc = w * slv;

        int beg = rfl(rowptr[node]), end = rfl(rowptr[node + 1]);
        int cnt = end - beg;
        const int* cp = csr + beg;
        int quads = cnt >> 2;
        if (quads > 0) {
            int i0 = rfl(cp[0]), i1 = rfl(cp[1]), i2 = rfl(cp[2]), i3 = rfl(cp[3]);
            float A = (xl + ((size_t)(unsigned)i0 << 6))[lane];
            float B = (xl + ((size_t)(unsigned)i1 << 6))[lane];
            float C = (xl + ((size_t)(unsigned)i2 << 6))[lane];
            float D = (xl + ((size_t)(unsigned)i3 << 6))[lane];
            for (int q = 1; q <= quads; ++q) {
                float nA = 0.f, nB = 0.f, nC = 0.f, nD = 0.f;
                if (q < quads) {
                    int j0 = rfl(cp[4 * q]), j1 = rfl(cp[4 * q + 1]);
                    int j2 = rfl(cp[4 * q + 2]), j3 = rfl(cp[4 * q + 3]);
                    nA = (xl + ((size_t)(unsigned)j0 << 6))[lane];
                    nB = (xl + ((size_t)(unsigned)j1 << 6))[lane];
                    nC = (xl + ((size_t)(unsigned)j2 << 6))[lane];
                    nD = (xl + ((size_t)(unsigned)j3 << 6))[lane];
                }
                float pa = lrelu(A + xrv) * a;
                float pb = lrelu(B + xrv) * a;
                float pc = lrelu(C + xrv) * a;
                float pd = lrelu(D + xrv) * a;
                dred4(pa, pb, pc, pd);
                float ea = __expf(rl63(pa)), eb = __expf(rl63(pb));
                float ec = __expf(rl63(pc)), ed = __expf(rl63(pd));
                den += (ea + eb) + (ec + ed);
                acc = fmaf(ea, A, fmaf(eb, B, fmaf(ec, C, fmaf(ed, D, acc))));
                A = nA; B = nB; C = nC; D = nD;
            }
        }
        for (int r = cnt & ~3; r < cnt; ++r) {
            int j = rfl(cp[r]);
            float Cv = (xl + ((size_t)(unsigned)j << 6))[lane];
            float pc = lrelu(Cv + xrv) * a;
            dred1(pc);
            float ec = __expf(rl63(pc));
            den += ec;
            acc = fmaf(ec, Cv, acc);
        }
        float o = acc / den + bv;
        out[nb + lane] = o > 0.f ? o : expm1f(o);
    }
}

// ---------- classifier head ----------
__global__ __launch_bounds__(256) void k_head(const float* __restrict__ H,
                                              const float* __restrict__ Wc,
                                              const float* __restrict__ bc,
                                              float* __restrict__ out) {
    __shared__ float Ws[NCLS * 64];
    __shared__ float bs[NCLS];
    for (int i = threadIdx.x; i < NCLS * 64; i += 256) Ws[i] = Wc[i];
    if (threadIdx.x < NCLS) bs[threadIdx.x] = bc[threadIdx.x];
    __syncthreads();
    int n = blockIdx.x * 256 + threadIdx.x;
    if (n >= N_NODES) return;
    const float4* hp = (const float4*)(H + (size_t)n * 64);
    float acc[NCLS] = {};
#pragma unroll
    for (int k4 = 0; k4 < 16; ++k4) {
        float4 hv = hp[k4];
#pragma unroll
        for (int c = 0; c < NCLS; ++c) {
            acc[c] = fmaf(hv.x, Ws[c * 64 + k4 * 4 + 0], acc[c]);
            acc[c] = fmaf(hv.y, Ws[c * 64 + k4 * 4 + 1], acc[c]);
            acc[c] = fmaf(hv.z, Ws[c * 64 + k4 * 4 + 2], acc[c]);
            acc[c] = fmaf(hv.w, Ws[c * 64 + k4 * 4 + 3], acc[c]);
        }
    }
#pragma unroll
    for (int c = 0; c < NCLS; ++c) out[(size_t)n * NCLS + c] = acc[c] + bs[c];
}

// ---------- launch ----------
extern "C" void kernel_launch(void* const* d_in, const int* in_sizes, int n_in,
                              void* d_out, int out_size, void* d_ws, size_t ws_size,
                              hipStream_t stream) {
    const float* x     = (const float*)d_in[0];
    const int*   ei    = (const int*)d_in[1];
    const int*   srcp  = ei;
    const int*   dstp  = ei + E_EDGES;
    const float* Wl1   = (const float*)d_in[3];
    const float* bl1   = (const float*)d_in[4];
    const float* Wr1   = (const float*)d_in[5];
    const float* br1   = (const float*)d_in[6];
    const float* att1  = (const float*)d_in[7];
    const float* bias1 = (const float*)d_in[8];
    const float* Wl2   = (const float*)d_in[9];
    const float* bl2   = (const float*)d_in[10];
    const float* Wr2   = (const float*)d_in[11];
    const float* br2   = (const float*)d_in[12];
    const float* att2  = (const float*)d_in[13];
    const float* bias2 = (const float*)d_in[14];
    const float* Wc    = (const float*)d_in[15];
    const float* bc    = (const float*)d_in[16];

    float* fA = (float*)d_ws;                       // xl1 [N,128] -> xl2 [N,64]
    float* fB = fA + (size_t)N_NODES * 128;         // xr1 [N,128] -> xr2 [N,64]
    float* fC = fB + (size_t)N_NODES * 128;         // h1  [N,128] -> h2  [N,64]
    int* rowptr = (int*)(fC + (size_t)N_NODES * 128);
    int* degcur = rowptr + (N_NODES + 1);
    int* csr    = degcur + N_NODES;
    // 16B-aligned bf16 weight splits after csr
    size_t woff = ((size_t)(csr + E_EDGES) - (size_t)d_ws + 15) & ~(size_t)15;
    short* whiL = (short*)((char*)d_ws + woff);     // 16384 each
    short* wloL = whiL + 16384;
    short* whiR = wloL + 16384;
    short* wloR = whiR + 16384;
    int* incl = (int*)(wloR + 16384);               // N ints
    int* bsum = incl + N_NODES;                     // SCAN_BLOCKS ints

    hipMemsetAsync(degcur, 0, N_NODES * sizeof(int), stream);
    k_count<<<(E_EDGES + 255) / 256, 256, 0, stream>>>(dstp, degcur);
    k_scanA<<<SCAN_BLOCKS, 256, 0, stream>>>(degcur, incl, bsum);
    k_scanB<<<1, 256, 0, stream>>>(bsum);
    k_scanC<<<SCAN_BLOCKS, 256, 0, stream>>>(degcur, incl, bsum, rowptr);
    k_scatter<<<(E_EDGES + 255) / 256, 256, 0, stream>>>(srcp, dstp, degcur, csr);

    int gblocks = (N_NODES + 63) / 64;

    // conv1: split weights, MFMA GEMMs (L/R separate, col-halves via grid.y)
    k_splitW<<<64, 256, 0, stream>>>(Wl1, 16384, whiL, wloL);
    k_splitW<<<64, 256, 0, stream>>>(Wr1, 16384, whiR, wloR);
    dim3 g1(gblocks, 2);
    k_mgemmS<128><<<g1, 256, 0, stream>>>(x, whiL, wloL, bl1, fA, N_NODES);
    k_mgemmS<128><<<g1, 256, 0, stream>>>(x, whiR, wloR, br1, fB, N_NODES);
    k_gat1<<<GAT_BLOCKS, 256, 0, stream>>>(fA, fB, rowptr, csr, att1, bias1, fC);

    // conv2
    k_splitW<<<32, 256, 0, stream>>>(Wl2, 8192, whiL, wloL);
    k_splitW<<<32, 256, 0, stream>>>(Wr2, 8192, whiR, wloR);
    dim3 g2(gblocks, 1);
    k_mgemmS<64><<<g2, 256, 0, stream>>>(fC, whiL, wloL, bl2, fA, N_NODES);
    k_mgemmS<64><<<g2, 256, 0, stream>>>(fC, whiR, wloR, br2, fB, N_NODES);
    k_gat2<<<GAT_BLOCKS, 256, 0, stream>>>(fA, fB, rowptr, csr, att2, bias2, fC);

    k_head<<<(N_NODES + 255) / 256, 256, 0, stream>>>(fC, Wc, bc, (float*)d_out);
}

// Round 13
// 412.886 us; speedup vs baseline: 1.0808x; 1.0808x over previous
//
#include <hip/hip_runtime.h>
#include <hip/hip_bf16.h>

#define N_NODES 50000
#define E_EDGES 800000
#define NCLS 10
#define SCAN_BLOCKS 196   // 196*256 = 50176 >= N_NODES

typedef short bfrag __attribute__((ext_vector_type(8)));   // 8 bf16 in 4 VGPRs
typedef float f32x4 __attribute__((ext_vector_type(4)));

__device__ __forceinline__ int rfl(int v) { return __builtin_amdgcn_readfirstlane(v); }

// ---------- bf16 split helpers ----------
__device__ __forceinline__ unsigned short bf16rne(float x) {
    unsigned u = __float_as_uint(x);
    unsigned r = u + 0x7FFFu + ((u >> 16) & 1u);
    return (unsigned short)(r >> 16);
}

// ---------- DPP wave-64 sum reductions ----------
template <int CTRL, int RM>
__device__ __forceinline__ float dppadd(float x) {
    int s = __builtin_amdgcn_update_dpp(0, __float_as_int(x), CTRL, RM, 0xf, true);
    return x + __int_as_float(s);
}
__device__ __forceinline__ float rl63(float x) {
    return __int_as_float(__builtin_amdgcn_readlane(__float_as_int(x), 63));
}
__device__ __forceinline__ float rl31(float x) {
    return __int_as_float(__builtin_amdgcn_readlane(__float_as_int(x), 31));
}
// full 64-lane reduce (total in lane 63): 6 stages
__device__ __forceinline__ void dred1(float& x0) {
    x0 = dppadd<0x111, 0xf>(x0);
    x0 = dppadd<0x112, 0xf>(x0);
    x0 = dppadd<0x114, 0xf>(x0);
    x0 = dppadd<0x118, 0xf>(x0);
    x0 = dppadd<0x142, 0xa>(x0);
    x0 = dppadd<0x143, 0xc>(x0);
}
__device__ __forceinline__ void dred4(float& x0, float& x1, float& x2, float& x3) {
    x0 = dppadd<0x111, 0xf>(x0); x1 = dppadd<0x111, 0xf>(x1);
    x2 = dppadd<0x111, 0xf>(x2); x3 = dppadd<0x111, 0xf>(x3);
    x0 = dppadd<0x112, 0xf>(x0); x1 = dppadd<0x112, 0xf>(x1);
    x2 = dppadd<0x112, 0xf>(x2); x3 = dppadd<0x112, 0xf>(x3);
    x0 = dppadd<0x114, 0xf>(x0); x1 = dppadd<0x114, 0xf>(x1);
    x2 = dppadd<0x114, 0xf>(x2); x3 = dppadd<0x114, 0xf>(x3);
    x0 = dppadd<0x118, 0xf>(x0); x1 = dppadd<0x118, 0xf>(x1);
    x2 = dppadd<0x118, 0xf>(x2); x3 = dppadd<0x118, 0xf>(x3);
    x0 = dppadd<0x142, 0xa>(x0); x1 = dppadd<0x142, 0xa>(x1);
    x2 = dppadd<0x142, 0xa>(x2); x3 = dppadd<0x142, 0xa>(x3);
    x0 = dppadd<0x143, 0xc>(x0); x1 = dppadd<0x143, 0xc>(x1);
    x2 = dppadd<0x143, 0xc>(x2); x3 = dppadd<0x143, 0xc>(x3);
}
// half-wave reduce, 5 stages: lane31 = sum(lanes 0-31), lane63 = sum(lanes 32-63)
__device__ __forceinline__ void dredH(float& x) {
    x = dppadd<0x111, 0xf>(x);
    x = dppadd<0x112, 0xf>(x);
    x = dppadd<0x114, 0xf>(x);
    x = dppadd<0x118, 0xf>(x);
    x = dppadd<0x142, 0xa>(x);
}
__device__ __forceinline__ void dredH2(float& x, float& y) {
    x = dppadd<0x111, 0xf>(x); y = dppadd<0x111, 0xf>(y);
    x = dppadd<0x112, 0xf>(x); y = dppadd<0x112, 0xf>(y);
    x = dppadd<0x114, 0xf>(x); y = dppadd<0x114, 0xf>(y);
    x = dppadd<0x118, 0xf>(x); y = dppadd<0x118, 0xf>(y);
    x = dppadd<0x142, 0xa>(x); y = dppadd<0x142, 0xa>(y);
}
__device__ __forceinline__ float lrelu(float u) { return u > 0.f ? u : 0.2f * u; }
// packed edge score partial: sum over 2 packed comps of lrelu(v+xr)*a
__device__ __forceinline__ float escore(float2 v, float2 xr2, float2 av) {
    float ux = v.x + xr2.x, uy = v.y + xr2.y;
    ux = fmaxf(ux, 0.2f * ux);
    uy = fmaxf(uy, 0.2f * uy);
    return ux * av.x + uy * av.y;
}

// ---------- CSR build ----------
__global__ void k_count(const int* __restrict__ dst, int* __restrict__ deg) {
    int i = blockIdx.x * blockDim.x + threadIdx.x;
    if (i < E_EDGES) {
        unsigned d = (unsigned)dst[i];
        if (d < N_NODES) atomicAdd(&deg[d], 1);
    }
}

// hierarchical exclusive scan, 3 passes, all parallel
__global__ void k_scanA(const int* __restrict__ deg, int* __restrict__ incl,
                        int* __restrict__ bsum) {
    __shared__ int s[256];
    int i = blockIdx.x * 256 + threadIdx.x;
    int v = (i < N_NODES) ? deg[i] : 0;
    s[threadIdx.x] = v;
    __syncthreads();
    for (int off = 1; off < 256; off <<= 1) {
        int t = (threadIdx.x >= off) ? s[threadIdx.x - off] : 0;
        __syncthreads();
        s[threadIdx.x] += t;
        __syncthreads();
    }
    if (i < N_NODES) incl[i] = s[threadIdx.x];
    if (threadIdx.x == 255) bsum[blockIdx.x] = s[255];
}

__global__ void k_scanB(int* __restrict__ bsum) {
    __shared__ int s[256];
    int t = threadIdx.x;
    s[t] = (t < SCAN_BLOCKS) ? bsum[t] : 0;
    __syncthreads();
    for (int off = 1; off < 256; off <<= 1) {
        int v = (t >= off) ? s[t - off] : 0;
        __syncthreads();
        s[t] += v;
        __syncthreads();
    }
    if (t < SCAN_BLOCKS) bsum[t] = s[t];  // inclusive block sums
}

__global__ void k_scanC(int* __restrict__ degcur, const int* __restrict__ incl,
                        const int* __restrict__ bsum, int* __restrict__ rowptr) {
    int i = blockIdx.x * 256 + threadIdx.x;
    if (i >= N_NODES) return;
    int base = (blockIdx.x == 0) ? 0 : bsum[blockIdx.x - 1];
    int d = degcur[i];
    int excl = base + incl[i] - d;
    rowptr[i] = excl;
    degcur[i] = excl;  // cursor init
    if (i == N_NODES - 1) rowptr[N_NODES] = base + incl[i];
}

__global__ void k_scatter(const int* __restrict__ src, const int* __restrict__ dst,
                          int* __restrict__ cursor, int* __restrict__ csr_src) {
    int i = blockIdx.x * blockDim.x + threadIdx.x;
    if (i < E_EDGES) {
        unsigned d = (unsigned)dst[i];
        if (d < N_NODES) {
            int p = atomicAdd(&cursor[d], 1);
            unsigned s = (unsigned)src[i];
            csr_src[p] = (s < N_NODES) ? (int)s : 0;
        }
    }
}

// ---------- split fp32 weights (L and R) -> hi/lo bf16, one launch ----------
__global__ void k_splitW2(const float* __restrict__ WL, const float* __restrict__ WR,
                          int n, short* __restrict__ hiL, short* __restrict__ loL,
                          short* __restrict__ hiR, short* __restrict__ loR) {
    int i = blockIdx.x * 256 + threadIdx.x;
    if (i < n) {
        float x = WL[i];
        unsigned short h = bf16rne(x);
        float hf = __uint_as_float((unsigned)h << 16);
        hiL[i] = (short)h;
        loL[i] = (short)bf16rne(x - hf);
        float y = WR[i];
        unsigned short h2 = bf16rne(y);
        float hf2 = __uint_as_float((unsigned)h2 << 16);
        hiR[i] = (short)h2;
        loR[i] = (short)bf16rne(y - hf2);
    }
}

// ---------- MFMA GEMM, L/R via blockIdx.z (split-bf16 fp32 emulation) ----------
// 64 cols per block via blockIdx.y. Live regs: A 32 + acc 16 + B 8 -> no spill.
template <int NOUT>
__global__ __launch_bounds__(256) void k_mgemmS(const float* __restrict__ X,
                                                const short* __restrict__ whiL,
                                                const short* __restrict__ wloL,
                                                const short* __restrict__ whiR,
                                                const short* __restrict__ wloR,
                                                const float* __restrict__ bL,
                                                const float* __restrict__ bR,
                                                float* __restrict__ YL,
                                                float* __restrict__ YR, int nrows) {
    const int NCT = 4;
    const short* whi = blockIdx.z ? whiR : whiL;
    const short* wlo = blockIdx.z ? wloR : wloL;
    const float* b   = blockIdx.z ? bR : bL;
    float* Y         = blockIdx.z ? YR : YL;
    int tid = threadIdx.x;
    int wv = tid >> 6, lane = tid & 63;
    int m = lane & 15, g = lane >> 4;
    int colbase = blockIdx.y * 64;
    int row = blockIdx.x * 64 + wv * 16 + m;
    int rowc = min(row, nrows - 1);

    bfrag ahi[4], alo[4];
    const float* xp = X + (size_t)rowc * 128 + g * 8;
#pragma unroll
    for (int kb = 0; kb < 4; ++kb) {
        float4 u0 = *(const float4*)(xp + kb * 32);
        float4 u1 = *(const float4*)(xp + kb * 32 + 4);
        float xs[8] = {u0.x, u0.y, u0.z, u0.w, u1.x, u1.y, u1.z, u1.w};
#pragma unroll
        for (int j = 0; j < 8; ++j) {
            unsigned short h = bf16rne(xs[j]);
            float hf = __uint_as_float((unsigned)h << 16);
            unsigned short l = bf16rne(xs[j] - hf);
            ahi[kb][j] = (short)h;
            alo[kb][j] = (short)l;
        }
    }

    f32x4 acc[NCT];
#pragma unroll
    for (int ct = 0; ct < NCT; ++ct) acc[ct] = (f32x4){0.f, 0.f, 0.f, 0.f};

#pragma unroll
    for (int kb = 0; kb < 4; ++kb) {
#pragma unroll
        for (int ct = 0; ct < NCT; ++ct) {
            size_t wo = (size_t)(colbase + ct * 16 + m) * 128 + kb * 32 + g * 8;
            bfrag bh = *(const bfrag*)(whi + wo);
            bfrag bl_ = *(const bfrag*)(wlo + wo);
            acc[ct] = __builtin_amdgcn_mfma_f32_16x16x32_bf16(ahi[kb], bh, acc[ct], 0, 0, 0);
            acc[ct] = __builtin_amdgcn_mfma_f32_16x16x32_bf16(alo[kb], bh, acc[ct], 0, 0, 0);
            acc[ct] = __builtin_amdgcn_mfma_f32_16x16x32_bf16(ahi[kb], bl_, acc[ct], 0, 0, 0);
        }
    }

    int orow0 = blockIdx.x * 64 + wv * 16 + g * 4;
#pragma unroll
    for (int ct = 0; ct < NCT; ++ct) {
        int col = colbase + ct * 16 + m;
        float bv = b[col];
#pragma unroll
        for (int i = 0; i < 4; ++i) {
            int orow = orow0 + i;
            if (orow < nrows) Y[(size_t)orow * NOUT + col] = acc[ct][i] + bv;
        }
    }
}

// ---------- GATv2 layer 1: H=2, C=64, concat -> out[N][128], fused bias+ELU ----------
// float2-packed halves (R10 form) + select-score-then-single-exp.
__global__ __launch_bounds__(256) void k_gat1(const float* __restrict__ xl,
                                              const float* __restrict__ xr,
                                              const int* __restrict__ rowptr,
                                              const int* __restrict__ csr,
                                              const float* __restrict__ att,
                                              const float* __restrict__ bias,
                                              float* __restrict__ out) {
    int node = blockIdx.x * 4 + (threadIdx.x >> 6);
    if (node >= N_NODES) return;
    node = rfl(node);
    int lane = threadIdx.x & 63;
    bool lo = lane < 32;
    const float2* xl2 = (const float2*)xl;
    size_t nb = (size_t)node * 64;   // row offset in float2 units (128 floats)
    float2 av = ((const float2*)att)[lane];
    float2 xr2 = ((const float2*)xr)[nb + lane];
    float2 sl2 = xl2[nb + lane];

    // self loop
    float p = escore(sl2, xr2, av);
    dredH(p);
    float sv = lo ? rl31(p) : rl63(p);
    float ev = __expf(sv);
    float den = ev;
    float2 acc;
    acc.x = ev * sl2.x;
    acc.y = ev * sl2.y;

    int beg = rfl(rowptr[node]), end = rfl(rowptr[node + 1]);
    int cnt = end - beg;
    int np = cnt >> 1;
    if (np > 0) {
        const int* cp = csr + beg;
        int i0 = rfl(cp[0]), i1 = rfl(cp[1]);
        float2 A = xl2[(size_t)(unsigned)i0 * 64 + lane];
        float2 B = xl2[(size_t)(unsigned)i1 * 64 + lane];
        for (int q = 1; q <= np; ++q) {
            float2 nA = {0.f, 0.f}, nB = {0.f, 0.f};
            if (q < np) {
                int j0 = rfl(cp[2 * q]), j1 = rfl(cp[2 * q + 1]);
                nA = xl2[(size_t)(unsigned)j0 * 64 + lane];
                nB = xl2[(size_t)(unsigned)j1 * 64 + lane];
            }
            float pa = escore(A, xr2, av);
            float pb = escore(B, xr2, av);
            dredH2(pa, pb);
            float sa = lo ? rl31(pa) : rl63(pa);
            float sb = lo ? rl31(pb) : rl63(pb);
            float eva = __expf(sa);
            float evb = __expf(sb);
            den += eva + evb;
            acc.x = fmaf(eva, A.x, fmaf(evb, B.x, acc.x));
            acc.y = fmaf(eva, A.y, fmaf(evb, B.y, acc.y));
            A = nA; B = nB;
        }
    }
    if (cnt & 1) {
        int j = rfl(csr[end - 1]);
        float2 C = xl2[(size_t)(unsigned)j * 64 + lane];
        float pc = escore(C, xr2, av);
        dredH(pc);
        float sc = lo ? rl31(pc) : rl63(pc);
        float evc = __expf(sc);
        den += evc;
        acc.x = fmaf(evc, C.x, acc.x);
        acc.y = fmaf(evc, C.y, acc.y);
    }
    float2 b2 = ((const float2*)bias)[lane];
    float ox = acc.x / den + b2.x;
    float oy = acc.y / den + b2.y;
    ox = ox > 0.f ? ox : expm1f(ox);
    oy = oy > 0.f ? oy : expm1f(oy);
    float2 o2 = {ox, oy};
    ((float2*)out)[nb + lane] = o2;
}

// ---------- GATv2 layer 2: H=1, C=64 -> out[N][64], fused bias+ELU (R10 form) ----------
__global__ __launch_bounds__(256) void k_gat2(const float* __restrict__ xl,
                                              const float* __restrict__ xr,
                                              const int* __restrict__ rowptr,
                                              const int* __restrict__ csr,
                                              const float* __restrict__ att,
                                              const float* __restrict__ bias,
                                              float* __restrict__ out) {
    int node = blockIdx.x * 4 + (threadIdx.x >> 6);
    if (node >= N_NODES) return;
    node = rfl(node);
    int lane = threadIdx.x & 63;
    float a = att[lane];
    size_t nb = (size_t)node << 6;
    float xrv = xr[nb + lane];
    float slv = xl[nb + lane];
    float p = lrelu(slv + xrv) * a;
    dred1(p);
    float w = __expf(rl63(p));
    float den = w;
    float acc = w * slv;

    int beg = rfl(rowptr[node]), end = rfl(rowptr[node + 1]);
    int cnt = end - beg;
    int quads = cnt >> 2;
    if (quads > 0) {
        const int* cp = csr + beg;
        int i0 = rfl(cp[0]), i1 = rfl(cp[1]), i2 = rfl(cp[2]), i3 = rfl(cp[3]);
        float A = (xl + ((size_t)(unsigned)i0 << 6))[lane];
        float B = (xl + ((size_t)(unsigned)i1 << 6))[lane];
        float C = (xl + ((size_t)(unsigned)i2 << 6))[lane];
        float D = (xl + ((size_t)(unsigned)i3 << 6))[lane];
        for (int q = 1; q <= quads; ++q) {
            float nA = 0.f, nB = 0.f, nC = 0.f, nD = 0.f;
            if (q < quads) {
                int j0 = rfl(cp[4 * q]), j1 = rfl(cp[4 * q + 1]);
                int j2 = rfl(cp[4 * q + 2]), j3 = rfl(cp[4 * q + 3]);
                nA = (xl + ((size_t)(unsigned)j0 << 6))[lane];
                nB = (xl + ((size_t)(unsigned)j1 << 6))[lane];
                nC = (xl + ((size_t)(unsigned)j2 << 6))[lane];
                nD = (xl + ((size_t)(unsigned)j3 << 6))[lane];
            }
            float pa = lrelu(A + xrv) * a;
            float pb = lrelu(B + xrv) * a;
            float pc = lrelu(C + xrv) * a;
            float pd = lrelu(D + xrv) * a;
            dred4(pa, pb, pc, pd);
            float ea = __expf(rl63(pa)), eb = __expf(rl63(pb));
            float ec = __expf(rl63(pc)), ed = __expf(rl63(pd));
            den += (ea + eb) + (ec + ed);
            acc = fmaf(ea, A, fmaf(eb, B, fmaf(ec, C, fmaf(ed, D, acc))));
            A = nA; B = nB; C = nC; D = nD;
        }
    }
    int rem = cnt & 3;
    if (rem) {
        int j0 = rfl(csr[end - rem]);
        int j1 = (rem > 1) ? rfl(csr[end - rem + 1]) : j0;
        int j2 = (rem > 2) ? rfl(csr[end - rem + 2]) : j0;
        float A = (xl + ((size_t)(unsigned)j0 << 6))[lane];
        float B = (xl + ((size_t)(unsigned)j1 << 6))[lane];
        float C = (xl + ((size_t)(unsigned)j2 << 6))[lane];
        float pa = lrelu(A + xrv) * a;
        float pb = lrelu(B + xrv) * a;
        float pc = lrelu(C + xrv) * a;
        float pd = 0.f;
        dred4(pa, pb, pc, pd);
        float ea = __expf(rl63(pa));
        float eb = (rem > 1) ? __expf(rl63(pb)) : 0.f;
        float ec = (rem > 2) ? __expf(rl63(pc)) : 0.f;
        den += ea + eb + ec;
        acc = fmaf(ea, A, fmaf(eb, B, fmaf(ec, C, acc)));
    }
    float o = acc / den + bias[lane];
    out[nb + lane] = o > 0.f ? o : expm1f(o);
}

// ---------- classifier head ----------
__global__ __launch_bounds__(256) void k_head(const float* __restrict__ H,
                                              const float* __restrict__ Wc,
                                              const float* __restrict__ bc,
                                              float* __restrict__ out) {
    __shared__ float Ws[NCLS * 64];
    __shared__ float bs[NCLS];
    for (int i = threadIdx.x; i < NCLS * 64; i += 256) Ws[i] = Wc[i];
    if (threadIdx.x < NCLS) bs[threadIdx.x] = bc[threadIdx.x];
    __syncthreads();
    int n = blockIdx.x * 256 + threadIdx.x;
    if (n >= N_NODES) return;
    const float4* hp = (const float4*)(H + (size_t)n * 64);
    float acc[NCLS] = {};
#pragma unroll
    for (int k4 = 0; k4 < 16; ++k4) {
        float4 hv = hp[k4];
#pragma unroll
        for (int c = 0; c < NCLS; ++c) {
            acc[c] = fmaf(hv.x, Ws[c * 64 + k4 * 4 + 0], acc[c]);
            acc[c] = fmaf(hv.y, Ws[c * 64 + k4 * 4 + 1], acc[c]);
            acc[c] = fmaf(hv.z, Ws[c * 64 + k4 * 4 + 2], acc[c]);
            acc[c] = fmaf(hv.w, Ws[c * 64 + k4 * 4 + 3], acc[c]);
        }
    }
#pragma unroll
    for (int c = 0; c < NCLS; ++c) out[(size_t)n * NCLS + c] = acc[c] + bs[c];
}

// ---------- launch ----------
extern "C" void kernel_launch(void* const* d_in, const int* in_sizes, int n_in,
                              void* d_out, int out_size, void* d_ws, size_t ws_size,
                              hipStream_t stream) {
    const float* x     = (const float*)d_in[0];
    const int*   ei    = (const int*)d_in[1];
    const int*   srcp  = ei;
    const int*   dstp  = ei + E_EDGES;
    const float* Wl1   = (const float*)d_in[3];
    const float* bl1   = (const float*)d_in[4];
    const float* Wr1   = (const float*)d_in[5];
    const float* br1   = (const float*)d_in[6];
    const float* att1  = (const float*)d_in[7];
    const float* bias1 = (const float*)d_in[8];
    const float* Wl2   = (const float*)d_in[9];
    const float* bl2   = (const float*)d_in[10];
    const float* Wr2   = (const float*)d_in[11];
    const float* br2   = (const float*)d_in[12];
    const float* att2  = (const float*)d_in[13];
    const float* bias2 = (const float*)d_in[14];
    const float* Wc    = (const float*)d_in[15];
    const float* bc    = (const float*)d_in[16];

    float* fA = (float*)d_ws;                       // xl1 [N,128] -> xl2 [N,64]
    float* fB = fA + (size_t)N_NODES * 128;         // xr1 [N,128] -> xr2 [N,64]
    float* fC = fB + (size_t)N_NODES * 128;         // h1  [N,128] -> h2  [N,64]
    int* rowptr = (int*)(fC + (size_t)N_NODES * 128);
    int* degcur = rowptr + (N_NODES + 1);
    int* csr    = degcur + N_NODES;
    // 16B-aligned bf16 weight splits after csr
    size_t woff = ((size_t)(csr + E_EDGES) - (size_t)d_ws + 15) & ~(size_t)15;
    short* whiL = (short*)((char*)d_ws + woff);     // 16384 each
    short* wloL = whiL + 16384;
    short* whiR = wloL + 16384;
    short* wloR = whiR + 16384;
    int* incl = (int*)(wloR + 16384);               // N ints
    int* bsum = incl + N_NODES;                     // SCAN_BLOCKS ints

    hipMemsetAsync(degcur, 0, N_NODES * sizeof(int), stream);
    k_count<<<(E_EDGES + 255) / 256, 256, 0, stream>>>(dstp, degcur);
    k_scanA<<<SCAN_BLOCKS, 256, 0, stream>>>(degcur, incl, bsum);
    k_scanB<<<1, 256, 0, stream>>>(bsum);
    k_scanC<<<SCAN_BLOCKS, 256, 0, stream>>>(degcur, incl, bsum, rowptr);
    k_scatter<<<(E_EDGES + 255) / 256, 256, 0, stream>>>(srcp, dstp, degcur, csr);

    int gblocks = (N_NODES + 63) / 64;

    // conv1: split both weights in one launch, one GEMM dispatch (L/R via z)
    k_splitW2<<<64, 256, 0, stream>>>(Wl1, Wr1, 16384, whiL, wloL, whiR, wloR);
    dim3 g1(gblocks, 2, 2);
    k_mgemmS<128><<<g1, 256, 0, stream>>>(x, whiL, wloL, whiR, wloR, bl1, br1, fA, fB, N_NODES);
    k_gat1<<<(N_NODES + 3) / 4, 256, 0, stream>>>(fA, fB, rowptr, csr, att1, bias1, fC);

    // conv2
    k_splitW2<<<32, 256, 0, stream>>>(Wl2, Wr2, 8192, whiL, wloL, whiR, wloR);
    dim3 g2(gblocks, 1, 2);
    k_mgemmS<64><<<g2, 256, 0, stream>>>(fC, whiL, wloL, whiR, wloR, bl2, br2, fA, fB, N_NODES);
    k_gat2<<<(N_NODES + 3) / 4, 256, 0, stream>>>(fA, fB, rowptr, csr, att2, bias2, fC);

    k_head<<<(N_NODES + 255) / 256, 256, 0, stream>>>(fC, Wc, bc, (float*)d_out);
}

// Round 14
// 359.943 us; speedup vs baseline: 1.2397x; 1.1471x over previous
//
#include <hip/hip_runtime.h>
#include <hip/hip_bf16.h>

#define N_NODES 50000
#define E_EDGES 800000
#define NCLS 10
#define SCAN_BLOCKS 196   // 196*256 = 50176 >= N_NODES

typedef short bfrag __attribute__((ext_vector_type(8)));   // 8 bf16 in 4 VGPRs
typedef float f32x4 __attribute__((ext_vector_type(4)));

__device__ __forceinline__ int rfl(int v) { return __builtin_amdgcn_readfirstlane(v); }

// ---------- bf16 split helpers ----------
__device__ __forceinline__ unsigned short bf16rne(float x) {
    unsigned u = __float_as_uint(x);
    unsigned r = u + 0x7FFFu + ((u >> 16) & 1u);
    return (unsigned short)(r >> 16);
}

// ---------- DPP wave-64 sum reductions ----------
template <int CTRL, int RM>
__device__ __forceinline__ float dppadd(float x) {
    int s = __builtin_amdgcn_update_dpp(0, __float_as_int(x), CTRL, RM, 0xf, true);
    return x + __int_as_float(s);
}
__device__ __forceinline__ float rl63(float x) {
    return __int_as_float(__builtin_amdgcn_readlane(__float_as_int(x), 63));
}
__device__ __forceinline__ float rl31(float x) {
    return __int_as_float(__builtin_amdgcn_readlane(__float_as_int(x), 31));
}
// full 64-lane reduce (total in lane 63): 6 stages
__device__ __forceinline__ void dred1(float& x0) {
    x0 = dppadd<0x111, 0xf>(x0);
    x0 = dppadd<0x112, 0xf>(x0);
    x0 = dppadd<0x114, 0xf>(x0);
    x0 = dppadd<0x118, 0xf>(x0);
    x0 = dppadd<0x142, 0xa>(x0);
    x0 = dppadd<0x143, 0xc>(x0);
}
__device__ __forceinline__ void dred4(float& x0, float& x1, float& x2, float& x3) {
    x0 = dppadd<0x111, 0xf>(x0); x1 = dppadd<0x111, 0xf>(x1);
    x2 = dppadd<0x111, 0xf>(x2); x3 = dppadd<0x111, 0xf>(x3);
    x0 = dppadd<0x112, 0xf>(x0); x1 = dppadd<0x112, 0xf>(x1);
    x2 = dppadd<0x112, 0xf>(x2); x3 = dppadd<0x112, 0xf>(x3);
    x0 = dppadd<0x114, 0xf>(x0); x1 = dppadd<0x114, 0xf>(x1);
    x2 = dppadd<0x114, 0xf>(x2); x3 = dppadd<0x114, 0xf>(x3);
    x0 = dppadd<0x118, 0xf>(x0); x1 = dppadd<0x118, 0xf>(x1);
    x2 = dppadd<0x118, 0xf>(x2); x3 = dppadd<0x118, 0xf>(x3);
    x0 = dppadd<0x142, 0xa>(x0); x1 = dppadd<0x142, 0xa>(x1);
    x2 = dppadd<0x142, 0xa>(x2); x3 = dppadd<0x142, 0xa>(x3);
    x0 = dppadd<0x143, 0xc>(x0); x1 = dppadd<0x143, 0xc>(x1);
    x2 = dppadd<0x143, 0xc>(x2); x3 = dppadd<0x143, 0xc>(x3);
}
// half-wave reduce, 5 stages: lane31 = sum(lanes 0-31), lane63 = sum(lanes 32-63)
__device__ __forceinline__ void dredH(float& x) {
    x = dppadd<0x111, 0xf>(x);
    x = dppadd<0x112, 0xf>(x);
    x = dppadd<0x114, 0xf>(x);
    x = dppadd<0x118, 0xf>(x);
    x = dppadd<0x142, 0xa>(x);
}
__device__ __forceinline__ void dredH2(float& x, float& y) {
    x = dppadd<0x111, 0xf>(x); y = dppadd<0x111, 0xf>(y);
    x = dppadd<0x112, 0xf>(x); y = dppadd<0x112, 0xf>(y);
    x = dppadd<0x114, 0xf>(x); y = dppadd<0x114, 0xf>(y);
    x = dppadd<0x118, 0xf>(x); y = dppadd<0x118, 0xf>(y);
    x = dppadd<0x142, 0xa>(x); y = dppadd<0x142, 0xa>(y);
}
__device__ __forceinline__ float lrelu(float u) { return u > 0.f ? u : 0.2f * u; }
// packed edge score partial: sum over 2 packed comps of lrelu(v+xr)*a
__device__ __forceinline__ float escore(float2 v, float2 xr2, float2 av) {
    float ux = v.x + xr2.x, uy = v.y + xr2.y;
    ux = fmaxf(ux, 0.2f * ux);
    uy = fmaxf(uy, 0.2f * uy);
    return ux * av.x + uy * av.y;
}

// ---------- CSR build ----------
__global__ void k_count(const int* __restrict__ dst, int* __restrict__ deg) {
    int i = blockIdx.x * blockDim.x + threadIdx.x;
    if (i < E_EDGES) {
        unsigned d = (unsigned)dst[i];
        if (d < N_NODES) atomicAdd(&deg[d], 1);
    }
}

// hierarchical exclusive scan, 3 passes, all parallel
__global__ void k_scanA(const int* __restrict__ deg, int* __restrict__ incl,
                        int* __restrict__ bsum) {
    __shared__ int s[256];
    int i = blockIdx.x * 256 + threadIdx.x;
    int v = (i < N_NODES) ? deg[i] : 0;
    s[threadIdx.x] = v;
    __syncthreads();
    for (int off = 1; off < 256; off <<= 1) {
        int t = (threadIdx.x >= off) ? s[threadIdx.x - off] : 0;
        __syncthreads();
        s[threadIdx.x] += t;
        __syncthreads();
    }
    if (i < N_NODES) incl[i] = s[threadIdx.x];
    if (threadIdx.x == 255) bsum[blockIdx.x] = s[255];
}

__global__ void k_scanB(int* __restrict__ bsum) {
    __shared__ int s[256];
    int t = threadIdx.x;
    s[t] = (t < SCAN_BLOCKS) ? bsum[t] : 0;
    __syncthreads();
    for (int off = 1; off < 256; off <<= 1) {
        int v = (t >= off) ? s[t - off] : 0;
        __syncthreads();
        s[t] += v;
        __syncthreads();
    }
    if (t < SCAN_BLOCKS) bsum[t] = s[t];  // inclusive block sums
}

__global__ void k_scanC(int* __restrict__ degcur, const int* __restrict__ incl,
                        const int* __restrict__ bsum, int* __restrict__ rowptr) {
    int i = blockIdx.x * 256 + threadIdx.x;
    if (i >= N_NODES) return;
    int base = (blockIdx.x == 0) ? 0 : bsum[blockIdx.x - 1];
    int d = degcur[i];
    int excl = base + incl[i] - d;
    rowptr[i] = excl;
    degcur[i] = excl;  // cursor init
    if (i == N_NODES - 1) rowptr[N_NODES] = base + incl[i];
}

__global__ void k_scatter(const int* __restrict__ src, const int* __restrict__ dst,
                          int* __restrict__ cursor, int* __restrict__ csr_src) {
    int i = blockIdx.x * blockDim.x + threadIdx.x;
    if (i < E_EDGES) {
        unsigned d = (unsigned)dst[i];
        if (d < N_NODES) {
            int p = atomicAdd(&cursor[d], 1);
            unsigned s = (unsigned)src[i];
            csr_src[p] = (s < N_NODES) ? (int)s : 0;
        }
    }
}

// ---------- split fp32 weights (L and R) -> hi/lo bf16, one launch ----------
__global__ void k_splitW2(const float* __restrict__ WL, const float* __restrict__ WR,
                          int n, short* __restrict__ hiL, short* __restrict__ loL,
                          short* __restrict__ hiR, short* __restrict__ loR) {
    int i = blockIdx.x * 256 + threadIdx.x;
    if (i < n) {
        float x = WL[i];
        unsigned short h = bf16rne(x);
        float hf = __uint_as_float((unsigned)h << 16);
        hiL[i] = (short)h;
        loL[i] = (short)bf16rne(x - hf);
        float y = WR[i];
        unsigned short h2 = bf16rne(y);
        float hf2 = __uint_as_float((unsigned)h2 << 16);
        hiR[i] = (short)h2;
        loR[i] = (short)bf16rne(y - hf2);
    }
}

// ---------- MFMA GEMM: W panel staged in LDS, RT row-tiles per block ----------
// L/R via blockIdx.z, 64-col panel via blockIdx.y. B-frags read from LDS
// (padded rows: 136 shorts -> ds_read_b128 is 2-way/free). No barrier in the
// row loop, so A-loads pipeline across row-tiles.
template <int NOUT, int RT>
__global__ __launch_bounds__(256) void k_mgemmS(const float* __restrict__ X,
                                                const short* __restrict__ whiL,
                                                const short* __restrict__ wloL,
                                                const short* __restrict__ whiR,
                                                const short* __restrict__ wloR,
                                                const float* __restrict__ bL,
                                                const float* __restrict__ bR,
                                                float* __restrict__ YL,
                                                float* __restrict__ YR, int nrows) {
    const int NCT = 4;
    const int KP = 136;  // padded row stride in shorts (128 + 8)
    __shared__ short Bhi[64 * KP];
    __shared__ short Blo[64 * KP];
    const short* whi = blockIdx.z ? whiR : whiL;
    const short* wlo = blockIdx.z ? wloR : wloL;
    const float* b   = blockIdx.z ? bR : bL;
    float* Y         = blockIdx.z ? YR : YL;
    int tid = threadIdx.x;
    int colbase = blockIdx.y * 64;

    // stage weight panel: 64 cols x 128 k, hi+lo, 8 shorts (int4) per chunk
    for (int idx = tid; idx < 64 * 16; idx += 256) {
        int col = idx >> 4;
        int k8 = (idx & 15) * 8;
        size_t srco = (size_t)(colbase + col) * 128 + k8;
        *(int4*)&Bhi[col * KP + k8] = *(const int4*)&whi[srco];
        *(int4*)&Blo[col * KP + k8] = *(const int4*)&wlo[srco];
    }
    __syncthreads();

    int wv = tid >> 6, lane = tid & 63;
    int m = lane & 15, g = lane >> 4;

    for (int rt = 0; rt < RT; ++rt) {
        int rti = blockIdx.x * RT + rt;
        if (rti * 64 >= nrows) break;
        int row = rti * 64 + wv * 16 + m;
        int rowc = min(row, nrows - 1);

        bfrag ahi[4], alo[4];
        const float* xp = X + (size_t)rowc * 128 + g * 8;
#pragma unroll
        for (int kb = 0; kb < 4; ++kb) {
            float4 u0 = *(const float4*)(xp + kb * 32);
            float4 u1 = *(const float4*)(xp + kb * 32 + 4);
            float xs[8] = {u0.x, u0.y, u0.z, u0.w, u1.x, u1.y, u1.z, u1.w};
#pragma unroll
            for (int j = 0; j < 8; ++j) {
                unsigned short h = bf16rne(xs[j]);
                float hf = __uint_as_float((unsigned)h << 16);
                unsigned short l = bf16rne(xs[j] - hf);
                ahi[kb][j] = (short)h;
                alo[kb][j] = (short)l;
            }
        }

        f32x4 acc[NCT];
#pragma unroll
        for (int ct = 0; ct < NCT; ++ct) acc[ct] = (f32x4){0.f, 0.f, 0.f, 0.f};

#pragma unroll
        for (int kb = 0; kb < 4; ++kb) {
#pragma unroll
            for (int ct = 0; ct < NCT; ++ct) {
                int lo_ = (ct * 16 + m) * KP + kb * 32 + g * 8;
                bfrag bh = *(const bfrag*)&Bhi[lo_];
                bfrag bl_ = *(const bfrag*)&Blo[lo_];
                acc[ct] = __builtin_amdgcn_mfma_f32_16x16x32_bf16(ahi[kb], bh, acc[ct], 0, 0, 0);
                acc[ct] = __builtin_amdgcn_mfma_f32_16x16x32_bf16(alo[kb], bh, acc[ct], 0, 0, 0);
                acc[ct] = __builtin_amdgcn_mfma_f32_16x16x32_bf16(ahi[kb], bl_, acc[ct], 0, 0, 0);
            }
        }

        int orow0 = rti * 64 + wv * 16 + g * 4;
#pragma unroll
        for (int ct = 0; ct < NCT; ++ct) {
            int col = colbase + ct * 16 + m;
            float bv = b[col];
#pragma unroll
            for (int i = 0; i < 4; ++i) {
                int orow = orow0 + i;
                if (orow < nrows) Y[(size_t)orow * NOUT + col] = acc[ct][i] + bv;
            }
        }
    }
}

// ---------- GATv2 layer 1: H=2, C=64, concat -> out[N][128], fused bias+ELU ----------
// float2-packed halves + select-score-then-single-exp.
__global__ __launch_bounds__(256) void k_gat1(const float* __restrict__ xl,
                                              const float* __restrict__ xr,
                                              const int* __restrict__ rowptr,
                                              const int* __restrict__ csr,
                                              const float* __restrict__ att,
                                              const float* __restrict__ bias,
                                              float* __restrict__ out) {
    int node = blockIdx.x * 4 + (threadIdx.x >> 6);
    if (node >= N_NODES) return;
    node = rfl(node);
    int lane = threadIdx.x & 63;
    bool lo = lane < 32;
    const float2* xl2 = (const float2*)xl;
    size_t nb = (size_t)node * 64;   // row offset in float2 units (128 floats)
    float2 av = ((const float2*)att)[lane];
    float2 xr2 = ((const float2*)xr)[nb + lane];
    float2 sl2 = xl2[nb + lane];

    // self loop
    float p = escore(sl2, xr2, av);
    dredH(p);
    float sv = lo ? rl31(p) : rl63(p);
    float ev = __expf(sv);
    float den = ev;
    float2 acc;
    acc.x = ev * sl2.x;
    acc.y = ev * sl2.y;

    int beg = rfl(rowptr[node]), end = rfl(rowptr[node + 1]);
    int cnt = end - beg;
    int np = cnt >> 1;
    if (np > 0) {
        const int* cp = csr + beg;
        int i0 = rfl(cp[0]), i1 = rfl(cp[1]);
        float2 A = xl2[(size_t)(unsigned)i0 * 64 + lane];
        float2 B = xl2[(size_t)(unsigned)i1 * 64 + lane];
        for (int q = 1; q <= np; ++q) {
            float2 nA = {0.f, 0.f}, nB = {0.f, 0.f};
            if (q < np) {
                int j0 = rfl(cp[2 * q]), j1 = rfl(cp[2 * q + 1]);
                nA = xl2[(size_t)(unsigned)j0 * 64 + lane];
                nB = xl2[(size_t)(unsigned)j1 * 64 + lane];
            }
            float pa = escore(A, xr2, av);
            float pb = escore(B, xr2, av);
            dredH2(pa, pb);
            float sa = lo ? rl31(pa) : rl63(pa);
            float sb = lo ? rl31(pb) : rl63(pb);
            float eva = __expf(sa);
            float evb = __expf(sb);
            den += eva + evb;
            acc.x = fmaf(eva, A.x, fmaf(evb, B.x, acc.x));
            acc.y = fmaf(eva, A.y, fmaf(evb, B.y, acc.y));
            A = nA; B = nB;
        }
    }
    if (cnt & 1) {
        int j = rfl(csr[end - 1]);
        float2 C = xl2[(size_t)(unsigned)j * 64 + lane];
        float pc = escore(C, xr2, av);
        dredH(pc);
        float sc = lo ? rl31(pc) : rl63(pc);
        float evc = __expf(sc);
        den += evc;
        acc.x = fmaf(evc, C.x, acc.x);
        acc.y = fmaf(evc, C.y, acc.y);
    }
    float2 b2 = ((const float2*)bias)[lane];
    float ox = acc.x / den + b2.x;
    float oy = acc.y / den + b2.y;
    ox = ox > 0.f ? ox : expm1f(ox);
    oy = oy > 0.f ? oy : expm1f(oy);
    float2 o2 = {ox, oy};
    ((float2*)out)[nb + lane] = o2;
}

// ---------- GATv2 layer 2: H=1, C=64 -> out[N][64], fused bias+ELU ----------
__global__ __launch_bounds__(256) void k_gat2(const float* __restrict__ xl,
                                              const float* __restrict__ xr,
                                              const int* __restrict__ rowptr,
                                              const int* __restrict__ csr,
                                              const float* __restrict__ att,
                                              const float* __restrict__ bias,
                                              float* __restrict__ out) {
    int node = blockIdx.x * 4 + (threadIdx.x >> 6);
    if (node >= N_NODES) return;
    node = rfl(node);
    int lane = threadIdx.x & 63;
    float a = att[lane];
    size_t nb = (size_t)node << 6;
    float xrv = xr[nb + lane];
    float slv = xl[nb + lane];
    float p = lrelu(slv + xrv) * a;
    dred1(p);
    float w = __expf(rl63(p));
    float den = w;
    float acc = w * slv;

    int beg = rfl(rowptr[node]), end = rfl(rowptr[node + 1]);
    int cnt = end - beg;
    int quads = cnt >> 2;
    if (quads > 0) {
        const int* cp = csr + beg;
        int i0 = rfl(cp[0]), i1 = rfl(cp[1]), i2 = rfl(cp[2]), i3 = rfl(cp[3]);
        float A = (xl + ((size_t)(unsigned)i0 << 6))[lane];
        float B = (xl + ((size_t)(unsigned)i1 << 6))[lane];
        float C = (xl + ((size_t)(unsigned)i2 << 6))[lane];
        float D = (xl + ((size_t)(unsigned)i3 << 6))[lane];
        for (int q = 1; q <= quads; ++q) {
            float nA = 0.f, nB = 0.f, nC = 0.f, nD = 0.f;
            if (q < quads) {
                int j0 = rfl(cp[4 * q]), j1 = rfl(cp[4 * q + 1]);
                int j2 = rfl(cp[4 * q + 2]), j3 = rfl(cp[4 * q + 3]);
                nA = (xl + ((size_t)(unsigned)j0 << 6))[lane];
                nB = (xl + ((size_t)(unsigned)j1 << 6))[lane];
                nC = (xl + ((size_t)(unsigned)j2 << 6))[lane];
                nD = (xl + ((size_t)(unsigned)j3 << 6))[lane];
            }
            float pa = lrelu(A + xrv) * a;
            float pb = lrelu(B + xrv) * a;
            float pc = lrelu(C + xrv) * a;
            float pd = lrelu(D + xrv) * a;
            dred4(pa, pb, pc, pd);
            float ea = __expf(rl63(pa)), eb = __expf(rl63(pb));
            float ec = __expf(rl63(pc)), ed = __expf(rl63(pd));
            den += (ea + eb) + (ec + ed);
            acc = fmaf(ea, A, fmaf(eb, B, fmaf(ec, C, fmaf(ed, D, acc))));
            A = nA; B = nB; C = nC; D = nD;
        }
    }
    int rem = cnt & 3;
    if (rem) {
        int j0 = rfl(csr[end - rem]);
        int j1 = (rem > 1) ? rfl(csr[end - rem + 1]) : j0;
        int j2 = (rem > 2) ? rfl(csr[end - rem + 2]) : j0;
        float A = (xl + ((size_t)(unsigned)j0 << 6))[lane];
        float B = (xl + ((size_t)(unsigned)j1 << 6))[lane];
        float C = (xl + ((size_t)(unsigned)j2 << 6))[lane];
        float pa = lrelu(A + xrv) * a;
        float pb = lrelu(B + xrv) * a;
        float pc = lrelu(C + xrv) * a;
        float pd = 0.f;
        dred4(pa, pb, pc, pd);
        float ea = __expf(rl63(pa));
        float eb = (rem > 1) ? __expf(rl63(pb)) : 0.f;
        float ec = (rem > 2) ? __expf(rl63(pc)) : 0.f;
        den += ea + eb + ec;
        acc = fmaf(ea, A, fmaf(eb, B, fmaf(ec, C, acc)));
    }
    float o = acc / den + bias[lane];
    out[nb + lane] = o > 0.f ? o : expm1f(o);
}

// ---------- classifier head ----------
__global__ __launch_bounds__(256) void k_head(const float* __restrict__ H,
                                              const float* __restrict__ Wc,
                                              const float* __restrict__ bc,
                                              float* __restrict__ out) {
    __shared__ float Ws[NCLS * 64];
    __shared__ float bs[NCLS];
    for (int i = threadIdx.x; i < NCLS * 64; i += 256) Ws[i] = Wc[i];
    if (threadIdx.x < NCLS) bs[threadIdx.x] = bc[threadIdx.x];
    __syncthreads();
    int n = blockIdx.x * 256 + threadIdx.x;
    if (n >= N_NODES) return;
    const float4* hp = (const float4*)(H + (size_t)n * 64);
    float acc[NCLS] = {};
#pragma unroll
    for (int k4 = 0; k4 < 16; ++k4) {
        float4 hv = hp[k4];
#pragma unroll
        for (int c = 0; c < NCLS; ++c) {
            acc[c] = fmaf(hv.x, Ws[c * 64 + k4 * 4 + 0], acc[c]);
            acc[c] = fmaf(hv.y, Ws[c * 64 + k4 * 4 + 1], acc[c]);
            acc[c] = fmaf(hv.z, Ws[c * 64 + k4 * 4 + 2], acc[c]);
            acc[c] = fmaf(hv.w, Ws[c * 64 + k4 * 4 + 3], acc[c]);
        }
    }
#pragma unroll
    for (int c = 0; c < NCLS; ++c) out[(size_t)n * NCLS + c] = acc[c] + bs[c];
}

// ---------- launch ----------
extern "C" void kernel_launch(void* const* d_in, const int* in_sizes, int n_in,
                              void* d_out, int out_size, void* d_ws, size_t ws_size,
                              hipStream_t stream) {
    const float* x     = (const float*)d_in[0];
    const int*   ei    = (const int*)d_in[1];
    const int*   srcp  = ei;
    const int*   dstp  = ei + E_EDGES;
    const float* Wl1   = (const float*)d_in[3];
    const float* bl1   = (const float*)d_in[4];
    const float* Wr1   = (const float*)d_in[5];
    const float* br1   = (const float*)d_in[6];
    const float* att1  = (const float*)d_in[7];
    const float* bias1 = (const float*)d_in[8];
    const float* Wl2   = (const float*)d_in[9];
    const float* bl2   = (const float*)d_in[10];
    const float* Wr2   = (const float*)d_in[11];
    const float* br2   = (const float*)d_in[12];
    const float* att2  = (const float*)d_in[13];
    const float* bias2 = (const float*)d_in[14];
    const float* Wc    = (const float*)d_in[15];
    const float* bc    = (const float*)d_in[16];

    float* fA = (float*)d_ws;                       // xl1 [N,128] -> xl2 [N,64]
    float* fB = fA + (size_t)N_NODES * 128;         // xr1 [N,128] -> xr2 [N,64]
    float* fC = fB + (size_t)N_NODES * 128;         // h1  [N,128] -> h2  [N,64]
    int* rowptr = (int*)(fC + (size_t)N_NODES * 128);
    int* degcur = rowptr + (N_NODES + 1);
    int* csr    = degcur + N_NODES;
    // 16B-aligned bf16 weight splits after csr
    size_t woff = ((size_t)(csr + E_EDGES) - (size_t)d_ws + 15) & ~(size_t)15;
    short* whiL = (short*)((char*)d_ws + woff);     // 16384 each
    short* wloL = whiL + 16384;
    short* whiR = wloL + 16384;
    short* wloR = whiR + 16384;
    int* incl = (int*)(wloR + 16384);               // N ints
    int* bsum = incl + N_NODES;                     // SCAN_BLOCKS ints

    hipMemsetAsync(degcur, 0, N_NODES * sizeof(int), stream);
    k_count<<<(E_EDGES + 255) / 256, 256, 0, stream>>>(dstp, degcur);
    k_scanA<<<SCAN_BLOCKS, 256, 0, stream>>>(degcur, incl, bsum);
    k_scanB<<<1, 256, 0, stream>>>(bsum);
    k_scanC<<<SCAN_BLOCKS, 256, 0, stream>>>(degcur, incl, bsum, rowptr);
    k_scatter<<<(E_EDGES + 255) / 256, 256, 0, stream>>>(srcp, dstp, degcur, csr);

    const int RT = 4;
    int gx = (N_NODES + 64 * RT - 1) / (64 * RT);   // 196

    // conv1: split both weights in one launch, one GEMM dispatch (L/R via z)
    k_splitW2<<<64, 256, 0, stream>>>(Wl1, Wr1, 16384, whiL, wloL, whiR, wloR);
    dim3 g1(gx, 2, 2);
    k_mgemmS<128, RT><<<g1, 256, 0, stream>>>(x, whiL, wloL, whiR, wloR, bl1, br1, fA, fB, N_NODES);
    k_gat1<<<(N_NODES + 3) / 4, 256, 0, stream>>>(fA, fB, rowptr, csr, att1, bias1, fC);

    // conv2
    k_splitW2<<<32, 256, 0, stream>>>(Wl2, Wr2, 8192, whiL, wloL, whiR, wloR);
    dim3 g2(gx, 1, 2);
    k_mgemmS<64, RT><<<g2, 256, 0, stream>>>(fC, whiL, wloL, whiR, wloR, bl2, br2, fA, fB, N_NODES);
    k_gat2<<<(N_NODES + 3) / 4, 256, 0, stream>>>(fA, fB, rowptr, csr, att2, bias2, fC);

    k_head<<<(N_NODES + 255) / 256, 256, 0, stream>>>(fC, Wc, bc, (float*)d_out);
}